// Round 1
// baseline (1239.054 us; speedup 1.0000x reference)
//
#include <hip/hip_runtime.h>
#include <hip/hip_bf16.h>

#define BB 4
#define NN 2048
#define DD 1024
#define HH 16
#define DHH 64
#define HB (HH*BB)   // 64

typedef __bf16 bf16;
typedef __bf16 bf16x8 __attribute__((ext_vector_type(8)));
typedef float f32x4 __attribute__((ext_vector_type(4)));

// ---------------- PE + add + cast to bf16 ----------------
// x[b,n,d] = data[b,n,d] + PE(n,d), stored bf16 row-major [8192][1024]
__global__ void pe_add_kernel(const float* __restrict__ data, bf16* __restrict__ xb) {
    int t = blockIdx.x * blockDim.x + threadIdx.x;
    int base = t * 4;                 // element index in [B*N*D)
    int row = base >> 10;             // / 1024
    int d0 = base & 1023;
    int n = row & (NN - 1);
    const float LOG2_10000 = 13.287712379549449f;
    int pn = n & ~1;
    float denom_p = exp2f((2.0f * (float)pn / (float)NN) * LOG2_10000);
    bool even_p = (n & 1) == 0;
    float4 dv = *(const float4*)(data + base);
    float din[4] = {dv.x, dv.y, dv.z, dv.w};
    #pragma unroll
    for (int u = 0; u < 4; ++u) {
        int d = d0 + u;
        int di = d & ~1;
        float denom_i = exp2f((2.0f * (float)di / (float)DD) * LOG2_10000);
        float a = (float)n / denom_i;
        float basev = ((d & 1) == 0) ? sinf(a) : cosf(a);
        float bm = (float)d / denom_p;
        float mult = even_p ? sinf(bm) : cosf(bm);
        xb[base + u] = (bf16)(din[u] + basev * mult);
    }
}

// ---------------- W transpose + cast: Wt[n][k] = W[k][n] ----------------
__global__ void wtrans_kernel(const float* __restrict__ W, bf16* __restrict__ Wt) {
    __shared__ float s[32][33];
    int bx = blockIdx.x * 32;  // n0
    int by = blockIdx.y * 32;  // k0
    int tx = threadIdx.x, ty = threadIdx.y;  // (32,8)
    #pragma unroll
    for (int i = 0; i < 32; i += 8)
        s[ty + i][tx] = W[(by + ty + i) * DD + bx + tx];
    __syncthreads();
    #pragma unroll
    for (int i = 0; i < 32; i += 8)
        Wt[(size_t)(bx + ty + i) * DD + by + tx] = (bf16)s[tx][ty + i];
}

// ---------------- QKV GEMM: C = xb @ W + bias, split-head epilogue ----------------
// one wave per 16x16 output tile; A,B frags both K-contiguous 16B loads.
// mode 0: Q -> dst[hb][n][dh] * 0.125 ; mode 1: K -> dst[hb][n][dh] ; mode 2: V -> dst[hb][dh][n]
__launch_bounds__(256)
__global__ void gemm_qkv_kernel(const bf16* __restrict__ A,    // [8192][1024]
                                const bf16* __restrict__ Wt,   // [1024][1024] (n,k)
                                const float* __restrict__ bias,
                                bf16* __restrict__ dst, int mode) {
    int wid = blockIdx.x * 4 + (threadIdx.x >> 6);
    int lane = threadIdx.x & 63;
    int quad = lane >> 4, l16 = lane & 15;
    int mtile = wid >> 6;   // 0..511
    int ntile = wid & 63;   // 0..63
    int m0 = mtile * 16, n0 = ntile * 16;
    const bf16* ap = A + (size_t)(m0 + l16) * DD + quad * 8;
    const bf16* bp = Wt + (size_t)(n0 + l16) * DD + quad * 8;
    f32x4 acc = {0.f, 0.f, 0.f, 0.f};
    #pragma unroll 4
    for (int k = 0; k < DD; k += 32) {
        bf16x8 af = *(const bf16x8*)(ap + k);
        bf16x8 bf = *(const bf16x8*)(bp + k);
        acc = __builtin_amdgcn_mfma_f32_16x16x32_bf16(af, bf, acc, 0, 0, 0);
    }
    int ncol = n0 + l16;
    float bv = bias[ncol];
    int h = ncol >> 6, dh = ncol & 63;
    #pragma unroll
    for (int r = 0; r < 4; ++r) {
        int mrow = m0 + quad * 4 + r;
        int b_ = mrow >> 11;       // /2048
        int n = mrow & 2047;
        int hb = h * BB + b_;
        float v = acc[r] + bv;
        if (mode == 0)      dst[((size_t)(hb * NN + n) * DHH) + dh] = (bf16)(v * 0.125f);
        else if (mode == 1) dst[((size_t)(hb * NN + n) * DHH) + dh] = (bf16)v;
        else                dst[((size_t)(hb * DHH + dh) * NN) + n] = (bf16)v;
    }
}

// ---------------- Flash attention: one wave per (hb, 16 q-rows) ----------------
__launch_bounds__(256)
__global__ void attn_kernel(const bf16* __restrict__ Qs,   // [hb][n][dh], pre-scaled
                            const bf16* __restrict__ Ks,   // [hb][n][dh]
                            const bf16* __restrict__ Vt,   // [hb][dh][n]
                            float* __restrict__ out) {     // [hb][n][dh]
    __shared__ bf16 pbuf[4][16 * 64];
    int wslot = threadIdx.x >> 6;
    int wid = blockIdx.x * 4 + wslot;
    int lane = threadIdx.x & 63;
    int quad = lane >> 4, l16 = lane & 15;
    int hb = wid >> 7;       // /128
    int qtile = wid & 127;
    int q0 = qtile * 16;
    const bf16* qbase = Qs + ((size_t)hb * NN + q0) * DHH;
    const bf16* kbase = Ks + (size_t)hb * NN * DHH;
    const bf16* vbase = Vt + (size_t)hb * DHH * NN;

    // Q A-frags: A[m=l16][k=quad*8+j (+32)]
    bf16x8 qf0 = *(const bf16x8*)(qbase + (size_t)l16 * DHH + quad * 8);
    bf16x8 qf1 = *(const bf16x8*)(qbase + (size_t)l16 * DHH + quad * 8 + 32);

    const f32x4 zero4 = {0.f, 0.f, 0.f, 0.f};
    float m_r[4], l_r[4];
    f32x4 o_acc[4];
    #pragma unroll
    for (int r = 0; r < 4; ++r) { m_r[r] = -1e30f; l_r[r] = 0.f; }
    #pragma unroll
    for (int t = 0; t < 4; ++t) o_acc[t] = zero4;

    bf16* pw = pbuf[wslot];

    for (int kt = 0; kt < NN; kt += 64) {
        // ---- scores S[16 q][64 k] as 4 col-tiles ----
        f32x4 s[4];
        #pragma unroll
        for (int t = 0; t < 4; ++t) {
            const bf16* krow = kbase + (size_t)(kt + t * 16 + l16) * DHH + quad * 8;
            bf16x8 kf0 = *(const bf16x8*)(krow);
            bf16x8 kf1 = *(const bf16x8*)(krow + 32);
            f32x4 z = zero4;
            z = __builtin_amdgcn_mfma_f32_16x16x32_bf16(qf0, kf0, z, 0, 0, 0);
            z = __builtin_amdgcn_mfma_f32_16x16x32_bf16(qf1, kf1, z, 0, 0, 0);
            s[t] = z;
        }
        // ---- online softmax (rows live on lanes sharing quad; reduce over lane&15) ----
        #pragma unroll
        for (int r = 0; r < 4; ++r) {
            float mx = fmaxf(fmaxf(s[0][r], s[1][r]), fmaxf(s[2][r], s[3][r]));
            #pragma unroll
            for (int off = 1; off < 16; off <<= 1)
                mx = fmaxf(mx, __shfl_xor(mx, off, 64));
            float mnew = fmaxf(m_r[r], mx);
            float alpha = __expf(m_r[r] - mnew);
            m_r[r] = mnew;
            float rs = 0.f;
            #pragma unroll
            for (int t = 0; t < 4; ++t) {
                float p = __expf(s[t][r] - mnew);
                s[t][r] = p;
                rs += p;
            }
            #pragma unroll
            for (int off = 1; off < 16; off <<= 1)
                rs += __shfl_xor(rs, off, 64);
            l_r[r] = l_r[r] * alpha + rs;
            #pragma unroll
            for (int t = 0; t < 4; ++t) o_acc[t][r] *= alpha;
        }
        // ---- P (C-layout regs) -> LDS row-major [16][64] -> A-frags ----
        #pragma unroll
        for (int t = 0; t < 4; ++t)
            #pragma unroll
            for (int r = 0; r < 4; ++r)
                pw[(quad * 4 + r) * 64 + t * 16 + l16] = (bf16)s[t][r];
        // same-wave LDS ops are in-order; no barrier needed (wave-private buffer)
        #pragma unroll
        for (int c = 0; c < 2; ++c) {
            bf16x8 pf = *(const bf16x8*)(pw + l16 * 64 + c * 32 + quad * 8);
            #pragma unroll
            for (int t = 0; t < 4; ++t) {
                const bf16* vrow = vbase + (size_t)(t * 16 + l16) * NN + kt + c * 32 + quad * 8;
                bf16x8 vf = *(const bf16x8*)vrow;
                o_acc[t] = __builtin_amdgcn_mfma_f32_16x16x32_bf16(pf, vf, o_acc[t], 0, 0, 0);
            }
        }
    }
    // ---- epilogue: O / l ----
    float* obase = out + ((size_t)hb * NN + q0) * DHH;
    #pragma unroll
    for (int r = 0; r < 4; ++r) {
        float inv = 1.0f / l_r[r];
        #pragma unroll
        for (int t = 0; t < 4; ++t)
            obase[(size_t)(quad * 4 + r) * DHH + t * 16 + l16] = o_acc[t][r] * inv;
    }
}

extern "C" void kernel_launch(void* const* d_in, const int* in_sizes, int n_in,
                              void* d_out, int out_size, void* d_ws, size_t ws_size,
                              hipStream_t stream) {
    const float* data = (const float*)d_in[0];
    const float* Wq   = (const float*)d_in[1];
    const float* bq   = (const float*)d_in[2];
    const float* Wk   = (const float*)d_in[3];
    const float* bk   = (const float*)d_in[4];
    const float* Wv   = (const float*)d_in[5];
    const float* bv   = (const float*)d_in[6];
    float* out = (float*)d_out;

    char* ws = (char*)d_ws;
    bf16* xb  = (bf16*)ws; ws += (size_t)8192 * 1024 * 2;
    bf16* wtq = (bf16*)ws; ws += (size_t)1024 * 1024 * 2;
    bf16* wtk = (bf16*)ws; ws += (size_t)1024 * 1024 * 2;
    bf16* wtv = (bf16*)ws; ws += (size_t)1024 * 1024 * 2;
    bf16* Qs  = (bf16*)ws; ws += (size_t)HB * NN * DHH * 2;
    bf16* Ks  = (bf16*)ws; ws += (size_t)HB * NN * DHH * 2;
    bf16* Vt  = (bf16*)ws; ws += (size_t)HB * NN * DHH * 2;
    // total ws use: 70 MB

    pe_add_kernel<<<8192, 256, 0, stream>>>(data, xb);
    dim3 tb(32, 8), tg(32, 32);
    wtrans_kernel<<<tg, tb, 0, stream>>>(Wq, wtq);
    wtrans_kernel<<<tg, tb, 0, stream>>>(Wk, wtk);
    wtrans_kernel<<<tg, tb, 0, stream>>>(Wv, wtv);
    gemm_qkv_kernel<<<8192, 256, 0, stream>>>(xb, wtq, bq, Qs, 0);
    gemm_qkv_kernel<<<8192, 256, 0, stream>>>(xb, wtk, bk, Ks, 1);
    gemm_qkv_kernel<<<8192, 256, 0, stream>>>(xb, wtv, bv, Vt, 2);
    attn_kernel<<<2048, 256, 0, stream>>>(Qs, Ks, Vt, out);
}

// Round 2
// 304.740 us; speedup vs baseline: 4.0659x; 4.0659x over previous
//
#include <hip/hip_runtime.h>
#include <hip/hip_bf16.h>
#include <hip/hip_fp16.h>

#define BB 4
#define NN 2048
#define DD 1024
#define HH 16
#define DHH 64
#define HB (HH*BB)   // 64

typedef __bf16 bf16;
typedef __bf16 bf16x8 __attribute__((ext_vector_type(8)));
typedef _Float16 f16x4 __attribute__((ext_vector_type(4)));
typedef float f32x4 __attribute__((ext_vector_type(4)));

__device__ __forceinline__ void async16(const void* g, void* l) {
    __builtin_amdgcn_global_load_lds(
        (const __attribute__((address_space(1))) unsigned int*)g,
        (__attribute__((address_space(3))) unsigned int*)l, 16, 0, 0);
}

// ---------------- PE + add + cast to bf16 ----------------
__global__ void pe_add_kernel(const float* __restrict__ data, bf16* __restrict__ xb) {
    int t = blockIdx.x * blockDim.x + threadIdx.x;
    int base = t * 4;
    int row = base >> 10;
    int d0 = base & 1023;
    int n = row & (NN - 1);
    const float LOG2_10000 = 13.287712379549449f;
    int pn = n & ~1;
    float denom_p = exp2f((2.0f * (float)pn / (float)NN) * LOG2_10000);
    bool even_p = (n & 1) == 0;
    float4 dv = *(const float4*)(data + base);
    float din[4] = {dv.x, dv.y, dv.z, dv.w};
    #pragma unroll
    for (int u = 0; u < 4; ++u) {
        int d = d0 + u;
        int di = d & ~1;
        float denom_i = exp2f((2.0f * (float)di / (float)DD) * LOG2_10000);
        float a = (float)n / denom_i;
        float basev = ((d & 1) == 0) ? __sinf(a) : __cosf(a);
        float bm = (float)d / denom_p;
        float mult = even_p ? __sinf(bm) : __cosf(bm);
        xb[base + u] = (bf16)(din[u] + basev * mult);
    }
}

// ---------------- W transpose + cast: Bw[z*1024 + n][k] = W_z[k][n] ----------------
__global__ void wtrans_kernel(const float* __restrict__ Wq, const float* __restrict__ Wk,
                              const float* __restrict__ Wv, bf16* __restrict__ Bw) {
    const float* W = (blockIdx.z == 0) ? Wq : (blockIdx.z == 1) ? Wk : Wv;
    bf16* Wt = Bw + (size_t)blockIdx.z * 1024 * 1024;
    __shared__ float s[32][33];
    int bx = blockIdx.x * 32;  // n0
    int by = blockIdx.y * 32;  // k0
    int tx = threadIdx.x, ty = threadIdx.y;  // (32,8)
    #pragma unroll
    for (int i = 0; i < 32; i += 8)
        s[ty + i][tx] = W[(by + ty + i) * DD + bx + tx];
    __syncthreads();
    #pragma unroll
    for (int i = 0; i < 32; i += 8)
        Wt[(size_t)(bx + ty + i) * DD + by + tx] = (bf16)s[tx][ty + i];
}

// ---------------- Fused QKV GEMM (m97 structure) ----------------
// C[8192][3072] = xb @ Bw^T ; epilogue splits heads:
// n<1024: Q -> Qs[hb][n][dh] * 0.125 ; n<2048: K -> Ks[hb][n][dh] ; else V -> Vh[hb][dh][n] (f16)
__launch_bounds__(256)
__global__ void gemm_qkv_fused(const bf16* __restrict__ A,   // [8192][1024]
                               const bf16* __restrict__ Bw,  // [3072][1024]
                               const float* __restrict__ bq, const float* __restrict__ bk,
                               const float* __restrict__ bv,
                               bf16* __restrict__ Qs, bf16* __restrict__ Ks,
                               __half* __restrict__ Vh) {
    __shared__ char smem[16384];
    bf16* As = (bf16*)smem;              // [128][32]
    bf16* Bs = (bf16*)(smem + 8192);     // [128][32]
    int tid = threadIdx.x;
    int w = tid >> 6, lane = tid & 63, quad = lane >> 4, l16 = lane & 15;
    int bm = blockIdx.x & 63, bn = blockIdx.x >> 6;
    int m0 = bm * 128, n0 = bn * 128;
    int wm = (w & 1) * 64, wn = (w >> 1) * 64;

    // staging: chunk c = r*256 + tid ; row = c>>2, kchunk = c&3 ; LDS byte = c*16
    const bf16* aS0 = A + (size_t)(m0 + (tid >> 2)) * DD + (tid & 3) * 8;
    const bf16* aS1 = A + (size_t)(m0 + 64 + (tid >> 2)) * DD + (tid & 3) * 8;
    const bf16* bS0 = Bw + (size_t)(n0 + (tid >> 2)) * DD + (tid & 3) * 8;
    const bf16* bS1 = Bw + (size_t)(n0 + 64 + (tid >> 2)) * DD + (tid & 3) * 8;
    char* aL0 = smem + w * 1024;
    char* aL1 = smem + 4096 + w * 1024;
    char* bL0 = smem + 8192 + w * 1024;
    char* bL1 = smem + 12288 + w * 1024;

    f32x4 acc[4][4];
    #pragma unroll
    for (int i = 0; i < 4; ++i)
        #pragma unroll
        for (int j = 0; j < 4; ++j) acc[i][j] = (f32x4){0.f, 0.f, 0.f, 0.f};

    for (int kk = 0; kk < DD; kk += 32) {
        async16(aS0 + kk, aL0);
        async16(aS1 + kk, aL1);
        async16(bS0 + kk, bL0);
        async16(bS1 + kk, bL1);
        __syncthreads();
        bf16x8 af[4], bfr[4];
        #pragma unroll
        for (int i = 0; i < 4; ++i)
            af[i] = *(const bf16x8*)(As + (wm + i * 16 + l16) * 32 + quad * 8);
        #pragma unroll
        for (int j = 0; j < 4; ++j)
            bfr[j] = *(const bf16x8*)(Bs + (wn + j * 16 + l16) * 32 + quad * 8);
        #pragma unroll
        for (int i = 0; i < 4; ++i)
            #pragma unroll
            for (int j = 0; j < 4; ++j)
                acc[i][j] = __builtin_amdgcn_mfma_f32_16x16x32_bf16(af[i], bfr[j], acc[i][j], 0, 0, 0);
        __syncthreads();
    }

    int mat = n0 >> 10;  // uniform per block
    const float* bias_p = (mat == 0) ? bq : (mat == 1) ? bk : bv;
    #pragma unroll
    for (int j = 0; j < 4; ++j) {
        int ng = n0 + wn + j * 16 + l16;
        int ncol = ng & 1023;
        float bias = bias_p[ncol];
        int h = ncol >> 6, dh = ncol & 63;
        #pragma unroll
        for (int i = 0; i < 4; ++i) {
            #pragma unroll
            for (int r = 0; r < 4; ++r) {
                int mrow = m0 + wm + i * 16 + quad * 4 + r;
                int b_ = mrow >> 11, nn_ = mrow & 2047;
                int hbi = h * BB + b_;
                float v = acc[i][j][r] + bias;
                if (mat == 0)      Qs[((size_t)hbi * NN + nn_) * DHH + dh] = (bf16)(v * 0.125f);
                else if (mat == 1) Ks[((size_t)hbi * NN + nn_) * DHH + dh] = (bf16)v;
                else               Vh[((size_t)hbi * DHH + dh) * NN + nn_] = (__half)v;
            }
        }
    }
}

// ---------------- Flash attention, S^T orientation ----------------
// block = 512 thr (8 waves, same hb). S^T = K*Q^T via mfma 16x16x32 bf16.
// P^T stays in regs as the B-operand of mfma_f32_16x16x16f16: O^T = V^T * P^T.
__launch_bounds__(512)
__global__ void attn_kernel(const bf16* __restrict__ Qs,   // [hb][n][dh], pre-scaled
                            const bf16* __restrict__ Ks,   // [hb][n][dh]
                            const __half* __restrict__ Vh, // [hb][dh][n]
                            float* __restrict__ out) {     // [hb][n][dh]
    __shared__ char smem[16384];   // K tile 8KB (swizzled) + V tile 8KB (swizzled)
    int tid = threadIdx.x;
    int w = tid >> 6, lane = tid & 63, quad = lane >> 4, l16 = lane & 15;
    int hb = blockIdx.x >> 4;
    int q0 = (blockIdx.x & 15) * 128 + w * 16;

    // Q as B-operand frags: B[n=q l16][k=dh quad*8+j]
    const bf16* qbase = Qs + ((size_t)hb * NN + q0) * DHH;
    bf16x8 qf0 = *(const bf16x8*)(qbase + (size_t)l16 * DHH + quad * 8);
    bf16x8 qf1 = *(const bf16x8*)(qbase + (size_t)l16 * DHH + quad * 8 + 32);

    // staging: lane i holds LDS chunk i; global chunk = (i&7)^((i>>3)&7) within row i>>3
    int srow = tid >> 3;
    int gch = (tid & 7) ^ (srow & 7);
    const bf16* ksrc = Ks + ((size_t)hb * NN + srow) * DHH + gch * 8;   // +kt*DHH per tile
    const __half* vsrc = Vh + ((size_t)hb * DHH + srow) * NN + gch * 8; // +kt per tile
    char* klds = smem + w * 1024;           // wave-uniform
    char* vlds = smem + 8192 + w * 1024;
    const bf16* ktile = (const bf16*)smem;
    const char* vtile = smem + 8192;

    float m_l = -1e30f, l_l = 0.f;
    f32x4 o[4];
    #pragma unroll
    for (int d = 0; d < 4; ++d) o[d] = (f32x4){0.f, 0.f, 0.f, 0.f};

    int kslot0 = (quad ^ (l16 & 7)) * 8;          // kf0 chunk offset (elements)
    int kslot1 = ((quad ^ 4) ^ (l16 & 7)) * 8;    // kf1

    for (int kt = 0; kt < NN; kt += 64) {
        async16(ksrc + (size_t)kt * DHH, klds);
        async16(vsrc + kt, vlds);
        __syncthreads();

        // S^T tiles: st[t] covers keys kt + t*16+quad*4+r, col q=l16
        f32x4 st[4];
        #pragma unroll
        for (int t = 0; t < 4; ++t) {
            int key = t * 16 + l16;
            bf16x8 kf0 = *(const bf16x8*)(ktile + key * 64 + kslot0);
            bf16x8 kf1 = *(const bf16x8*)(ktile + key * 64 + kslot1);
            f32x4 z = (f32x4){0.f, 0.f, 0.f, 0.f};
            z = __builtin_amdgcn_mfma_f32_16x16x32_bf16(kf0, qf0, z, 0, 0, 0);
            z = __builtin_amdgcn_mfma_f32_16x16x32_bf16(kf1, qf1, z, 0, 0, 0);
            st[t] = z;
        }

        // online softmax: per-lane q=l16; 16 in-reg values + 2 shfl steps across quads
        float mx = st[0][0];
        #pragma unroll
        for (int t = 0; t < 4; ++t)
            #pragma unroll
            for (int r = 0; r < 4; ++r) mx = fmaxf(mx, st[t][r]);
        mx = fmaxf(mx, __shfl_xor(mx, 16, 64));
        mx = fmaxf(mx, __shfl_xor(mx, 32, 64));
        float mnew = fmaxf(m_l, mx);
        float alpha = __expf(m_l - mnew);
        m_l = mnew;
        float rs = 0.f;
        f16x4 p16[4];
        #pragma unroll
        for (int t = 0; t < 4; ++t) {
            #pragma unroll
            for (int r = 0; r < 4; ++r) {
                float p = __expf(st[t][r] - mnew);
                rs += p;
                p16[t][r] = (_Float16)p;
            }
        }
        rs += __shfl_xor(rs, 16, 64);
        rs += __shfl_xor(rs, 32, 64);
        l_l = l_l * alpha + rs;
        #pragma unroll
        for (int d = 0; d < 4; ++d) o[d] *= alpha;

        // O^T += V^T * P^T : A-frag from LDS V tile, B-frag = p16 regs
        #pragma unroll
        for (int d = 0; d < 4; ++d) {
            #pragma unroll
            for (int s = 0; s < 4; ++s) {
                int kc = s * 2 + (quad >> 1);
                int slot = kc ^ (l16 & 7);
                f16x4 vf = *(const f16x4*)(vtile + (d * 16 + l16) * 128 + slot * 16 + (quad & 1) * 8);
                o[d] = __builtin_amdgcn_mfma_f32_16x16x16f16(vf, p16[s], o[d], 0, 0, 0);
            }
        }
        __syncthreads();
    }

    // epilogue: element (dh = d*16+quad*4+r, q = l16) -> out[hb][q][dh]
    float inv = 1.0f / l_l;
    float* ob = out + ((size_t)hb * NN + q0 + l16) * DHH + quad * 4;
    #pragma unroll
    for (int d = 0; d < 4; ++d) {
        f32x4 vv = o[d] * inv;
        *(f32x4*)(ob + d * 16) = vv;
    }
}

extern "C" void kernel_launch(void* const* d_in, const int* in_sizes, int n_in,
                              void* d_out, int out_size, void* d_ws, size_t ws_size,
                              hipStream_t stream) {
    const float* data = (const float*)d_in[0];
    const float* Wq   = (const float*)d_in[1];
    const float* bq   = (const float*)d_in[2];
    const float* Wk   = (const float*)d_in[3];
    const float* bk   = (const float*)d_in[4];
    const float* Wv   = (const float*)d_in[5];
    const float* bv   = (const float*)d_in[6];
    float* out = (float*)d_out;

    char* ws = (char*)d_ws;
    bf16* xb = (bf16*)ws; ws += (size_t)8192 * 1024 * 2;       // 16 MB
    bf16* Bw = (bf16*)ws; ws += (size_t)3072 * 1024 * 2;       // 6 MB
    bf16* Qs = (bf16*)ws; ws += (size_t)HB * NN * DHH * 2;     // 16 MB
    bf16* Ks = (bf16*)ws; ws += (size_t)HB * NN * DHH * 2;     // 16 MB
    __half* Vh = (__half*)ws; ws += (size_t)HB * NN * DHH * 2; // 16 MB

    pe_add_kernel<<<8192, 256, 0, stream>>>(data, xb);
    dim3 tb(32, 8), tg(32, 32, 3);
    wtrans_kernel<<<tg, tb, 0, stream>>>(Wq, Wk, Wv, Bw);
    gemm_qkv_fused<<<1536, 256, 0, stream>>>(xb, Bw, bq, bk, bv, Qs, Ks, Vh);
    attn_kernel<<<1024, 512, 0, stream>>>(Qs, Ks, Vh, out);
}

// Round 3
// 269.422 us; speedup vs baseline: 4.5989x; 1.1311x over previous
//
#include <hip/hip_runtime.h>
#include <hip/hip_bf16.h>
#include <hip/hip_fp16.h>

#define BB 4
#define NN 2048
#define DD 1024
#define HH 16
#define DHH 64
#define HB (HH*BB)   // 64

typedef __bf16 bf16;
typedef __bf16 bf16x4 __attribute__((ext_vector_type(4)));
typedef __bf16 bf16x8 __attribute__((ext_vector_type(8)));
typedef _Float16 f16x4 __attribute__((ext_vector_type(4)));
typedef float f32x4 __attribute__((ext_vector_type(4)));

// Q pre-scale: (1/sqrt(64)) * log2(e) so softmax runs in exp2 domain
#define QSCALE 0.18033688011112042f

__device__ __forceinline__ void async16(const void* g, void* l) {
    __builtin_amdgcn_global_load_lds(
        (const __attribute__((address_space(1))) unsigned int*)g,
        (__attribute__((address_space(3))) unsigned int*)l, 16, 0, 0);
}

// ---------------- PE + add + cast to bf16 ----------------
__global__ void pe_add_kernel(const float* __restrict__ data, bf16* __restrict__ xb) {
    int t = blockIdx.x * blockDim.x + threadIdx.x;
    int base = t * 4;
    int row = base >> 10;
    int d0 = base & 1023;
    int n = row & (NN - 1);
    const float LOG2_10000 = 13.287712379549449f;
    int pn = n & ~1;
    float denom_p = exp2f((2.0f * (float)pn / (float)NN) * LOG2_10000);
    bool even_p = (n & 1) == 0;
    float4 dv = *(const float4*)(data + base);
    float din[4] = {dv.x, dv.y, dv.z, dv.w};
    bf16x4 ov;
    #pragma unroll
    for (int u = 0; u < 4; ++u) {
        int d = d0 + u;
        int di = d & ~1;
        float denom_i = exp2f((2.0f * (float)di / (float)DD) * LOG2_10000);
        float a = (float)n / denom_i;
        float basev = ((d & 1) == 0) ? __sinf(a) : __cosf(a);
        float bm = (float)d / denom_p;
        float mult = even_p ? __sinf(bm) : __cosf(bm);
        ov[u] = (bf16)(din[u] + basev * mult);
    }
    *(bf16x4*)(xb + base) = ov;
}

// ---------------- W transpose + cast: Bw[z*1024 + n][k] = W_z[k][n] ----------------
__global__ void wtrans_kernel(const float* __restrict__ Wq, const float* __restrict__ Wk,
                              const float* __restrict__ Wv, bf16* __restrict__ Bw) {
    const float* W = (blockIdx.z == 0) ? Wq : (blockIdx.z == 1) ? Wk : Wv;
    bf16* Wt = Bw + (size_t)blockIdx.z * 1024 * 1024;
    __shared__ float s[32][33];
    int bx = blockIdx.x * 32;  // n0
    int by = blockIdx.y * 32;  // k0
    int tx = threadIdx.x, ty = threadIdx.y;  // (32,8)
    #pragma unroll
    for (int i = 0; i < 32; i += 8)
        s[ty + i][tx] = W[(by + ty + i) * DD + bx + tx];
    __syncthreads();
    #pragma unroll
    for (int i = 0; i < 32; i += 8)
        Wt[(size_t)(bx + ty + i) * DD + by + tx] = (bf16)s[tx][ty + i];
}

// ---------------- Fused QKV GEMM (double-buffered m97 structure) ----------------
__launch_bounds__(256)
__global__ void gemm_qkv_fused(const bf16* __restrict__ A,   // [8192][1024]
                               const bf16* __restrict__ Bw,  // [3072][1024]
                               const float* __restrict__ bq, const float* __restrict__ bk,
                               const float* __restrict__ bv,
                               bf16* __restrict__ Qs, bf16* __restrict__ Ks,
                               __half* __restrict__ Vh) {
    __shared__ char smem[32768];   // 2 x (A 8KB + B 8KB)
    int tid = threadIdx.x;
    int w = tid >> 6, lane = tid & 63, quad = lane >> 4, l16 = lane & 15;
    int bm = blockIdx.x & 63, bn = blockIdx.x >> 6;
    int m0 = bm * 128, n0 = bn * 128;
    int wm = (w & 1) * 64, wn = (w >> 1) * 64;

    const bf16* aS0 = A + (size_t)(m0 + (tid >> 2)) * DD + (tid & 3) * 8;
    const bf16* aS1 = aS0 + (size_t)64 * DD;
    const bf16* bS0 = Bw + (size_t)(n0 + (tid >> 2)) * DD + (tid & 3) * 8;
    const bf16* bS1 = bS0 + (size_t)64 * DD;

    f32x4 acc[4][4];
    #pragma unroll
    for (int i = 0; i < 4; ++i)
        #pragma unroll
        for (int j = 0; j < 4; ++j) acc[i][j] = (f32x4){0.f, 0.f, 0.f, 0.f};

    // prefetch k-step 0 into buffer 0
    async16(aS0, smem + w * 1024);
    async16(aS1, smem + 4096 + w * 1024);
    async16(bS0, smem + 8192 + w * 1024);
    async16(bS1, smem + 12288 + w * 1024);
    __syncthreads();

    for (int kk = 0; kk < DD; kk += 32) {
        char* buf  = smem + ((kk >> 5) & 1) * 16384;
        char* nbuf = smem + (((kk >> 5) & 1) ^ 1) * 16384;
        if (kk + 32 < DD) {
            async16(aS0 + kk + 32, nbuf + w * 1024);
            async16(aS1 + kk + 32, nbuf + 4096 + w * 1024);
            async16(bS0 + kk + 32, nbuf + 8192 + w * 1024);
            async16(bS1 + kk + 32, nbuf + 12288 + w * 1024);
        }
        const bf16* As = (const bf16*)buf;
        const bf16* Bs = (const bf16*)(buf + 8192);
        bf16x8 af[4], bfr[4];
        #pragma unroll
        for (int i = 0; i < 4; ++i)
            af[i] = *(const bf16x8*)(As + (wm + i * 16 + l16) * 32 + quad * 8);
        #pragma unroll
        for (int j = 0; j < 4; ++j)
            bfr[j] = *(const bf16x8*)(Bs + (wn + j * 16 + l16) * 32 + quad * 8);
        #pragma unroll
        for (int i = 0; i < 4; ++i)
            #pragma unroll
            for (int j = 0; j < 4; ++j)
                acc[i][j] = __builtin_amdgcn_mfma_f32_16x16x32_bf16(af[i], bfr[j], acc[i][j], 0, 0, 0);
        __syncthreads();
    }

    int mat = n0 >> 10;  // uniform per block
    const float* bias_p = (mat == 0) ? bq : (mat == 1) ? bk : bv;
    #pragma unroll
    for (int j = 0; j < 4; ++j) {
        int ncol = (n0 + wn + j * 16 + l16) & 1023;
        float bias = bias_p[ncol];
        int h = ncol >> 6, dh = ncol & 63;
        #pragma unroll
        for (int i = 0; i < 4; ++i) {
            int mrow0 = m0 + wm + i * 16 + quad * 4;   // multiple of 4, same b_ for r=0..3
            int b_ = mrow0 >> 11, nn0 = mrow0 & 2047;
            int hbi = h * BB + b_;
            if (mat == 0) {
                bf16* qp = Qs + ((size_t)hbi * NN + nn0) * DHH + dh;
                #pragma unroll
                for (int r = 0; r < 4; ++r)
                    qp[(size_t)r * DHH] = (bf16)((acc[i][j][r] + bias) * QSCALE);
            } else if (mat == 1) {
                bf16* kp = Ks + ((size_t)hbi * NN + nn0) * DHH + dh;
                #pragma unroll
                for (int r = 0; r < 4; ++r)
                    kp[(size_t)r * DHH] = (bf16)(acc[i][j][r] + bias);
            } else {
                __half* vp = Vh + ((size_t)hbi * DHH + dh) * NN + nn0;
                f16x4 vv;
                #pragma unroll
                for (int r = 0; r < 4; ++r) vv[r] = (_Float16)(acc[i][j][r] + bias);
                *(f16x4*)vp = vv;
            }
        }
    }
}

// ---------------- Flash attention, S^T orientation, double-buffered ----------------
__launch_bounds__(512)
__global__ void attn_kernel(const bf16* __restrict__ Qs,   // [hb][n][dh], pre-scaled by QSCALE
                            const bf16* __restrict__ Ks,   // [hb][n][dh]
                            const __half* __restrict__ Vh, // [hb][dh][n]
                            float* __restrict__ out) {     // [hb][n][dh]
    __shared__ char smem[32768];   // 2 x (K 8KB + V 8KB)
    int tid = threadIdx.x;
    int w = tid >> 6, lane = tid & 63, quad = lane >> 4, l16 = lane & 15;
    int bi = blockIdx.x;
    // XCD-swizzle: same-hb blocks land on the same XCD (bi%8 picks XCD)
    int hb = (bi & 7) | (((bi >> 7) & 7) << 3);
    int q0 = ((bi >> 3) & 15) * 128 + w * 16;

    const bf16* qbase = Qs + ((size_t)hb * NN + q0) * DHH;
    bf16x8 qf0 = *(const bf16x8*)(qbase + (size_t)l16 * DHH + quad * 8);
    bf16x8 qf1 = *(const bf16x8*)(qbase + (size_t)l16 * DHH + quad * 8 + 32);

    // staging: lane tid stages row srow, xor-swizzled chunk gch
    int srow = tid >> 3;
    int gch = (tid & 7) ^ (srow & 7);
    const bf16* ksrc = Ks + ((size_t)hb * NN + srow) * DHH + gch * 8;
    const __half* vsrc = Vh + ((size_t)hb * DHH + srow) * NN + gch * 8;

    float m_l = -1e30f;
    f32x4 l_acc = {0.f, 0.f, 0.f, 0.f};
    f32x4 o[4];
    #pragma unroll
    for (int d = 0; d < 4; ++d) o[d] = (f32x4){0.f, 0.f, 0.f, 0.f};
    const f16x4 ones = {(_Float16)1.f, (_Float16)1.f, (_Float16)1.f, (_Float16)1.f};

    int kslot0 = (quad ^ (l16 & 7)) * 8;
    int kslot1 = ((quad ^ 4) ^ (l16 & 7)) * 8;

    // prefetch tile 0 into buffer 0
    async16(ksrc, smem + w * 1024);
    async16(vsrc, smem + 8192 + w * 1024);
    __syncthreads();

    for (int kt = 0; kt < NN; kt += 64) {
        char* buf  = smem + ((kt >> 6) & 1) * 16384;
        char* nbuf = smem + (((kt >> 6) & 1) ^ 1) * 16384;
        if (kt + 64 < NN) {
            async16(ksrc + (size_t)(kt + 64) * DHH, nbuf + w * 1024);
            async16(vsrc + (kt + 64), nbuf + 8192 + w * 1024);
        }
        const bf16* ktile = (const bf16*)buf;
        const char* vtile = buf + 8192;

        // S^T tiles (log2 domain): st[t] keys kt+t*16+quad*4+r, col q=l16
        f32x4 st[4];
        #pragma unroll
        for (int t = 0; t < 4; ++t) {
            int key = t * 16 + l16;
            bf16x8 kf0 = *(const bf16x8*)(ktile + key * 64 + kslot0);
            bf16x8 kf1 = *(const bf16x8*)(ktile + key * 64 + kslot1);
            f32x4 z = (f32x4){0.f, 0.f, 0.f, 0.f};
            z = __builtin_amdgcn_mfma_f32_16x16x32_bf16(kf0, qf0, z, 0, 0, 0);
            z = __builtin_amdgcn_mfma_f32_16x16x32_bf16(kf1, qf1, z, 0, 0, 0);
            st[t] = z;
        }

        // online softmax (exp2 domain)
        float mx = st[0][0];
        #pragma unroll
        for (int t = 0; t < 4; ++t)
            #pragma unroll
            for (int r = 0; r < 4; ++r) mx = fmaxf(mx, st[t][r]);
        mx = fmaxf(mx, __shfl_xor(mx, 16, 64));
        mx = fmaxf(mx, __shfl_xor(mx, 32, 64));
        float mnew = fmaxf(m_l, mx);
        float alpha = __builtin_amdgcn_exp2f(m_l - mnew);
        m_l = mnew;
        f16x4 p16[4];
        #pragma unroll
        for (int t = 0; t < 4; ++t) {
            #pragma unroll
            for (int r = 0; r < 4; ++r) {
                float p = __builtin_amdgcn_exp2f(st[t][r] - mnew);
                p16[t][r] = (_Float16)p;
            }
        }
        #pragma unroll
        for (int d = 0; d < 4; ++d) o[d] *= alpha;
        l_acc *= alpha;

        // O^T += V^T * P^T ; l_acc += 1 * P^T (row-sum via MFMA)
        #pragma unroll
        for (int d = 0; d < 4; ++d) {
            #pragma unroll
            for (int s = 0; s < 4; ++s) {
                int kc = s * 2 + (quad >> 1);
                int slot = kc ^ (l16 & 7);
                f16x4 vf = *(const f16x4*)(vtile + (d * 16 + l16) * 128 + slot * 16 + (quad & 1) * 8);
                o[d] = __builtin_amdgcn_mfma_f32_16x16x16f16(vf, p16[s], o[d], 0, 0, 0);
            }
        }
        #pragma unroll
        for (int s = 0; s < 4; ++s)
            l_acc = __builtin_amdgcn_mfma_f32_16x16x16f16(ones, p16[s], l_acc, 0, 0, 0);

        __syncthreads();
    }

    float inv = 1.0f / l_acc[0];
    float* ob = out + ((size_t)hb * NN + q0 + l16) * DHH + quad * 4;
    #pragma unroll
    for (int d = 0; d < 4; ++d) {
        f32x4 vv = o[d] * inv;
        *(f32x4*)(ob + d * 16) = vv;
    }
}

extern "C" void kernel_launch(void* const* d_in, const int* in_sizes, int n_in,
                              void* d_out, int out_size, void* d_ws, size_t ws_size,
                              hipStream_t stream) {
    const float* data = (const float*)d_in[0];
    const float* Wq   = (const float*)d_in[1];
    const float* bq   = (const float*)d_in[2];
    const float* Wk   = (const float*)d_in[3];
    const float* bk   = (const float*)d_in[4];
    const float* Wv   = (const float*)d_in[5];
    const float* bv   = (const float*)d_in[6];
    float* out = (float*)d_out;

    char* ws = (char*)d_ws;
    bf16* xb = (bf16*)ws; ws += (size_t)8192 * 1024 * 2;       // 16 MB
    bf16* Bw = (bf16*)ws; ws += (size_t)3072 * 1024 * 2;       // 6 MB
    bf16* Qs = (bf16*)ws; ws += (size_t)HB * NN * DHH * 2;     // 16 MB
    bf16* Ks = (bf16*)ws; ws += (size_t)HB * NN * DHH * 2;     // 16 MB
    __half* Vh = (__half*)ws; ws += (size_t)HB * NN * DHH * 2; // 16 MB

    pe_add_kernel<<<8192, 256, 0, stream>>>(data, xb);
    dim3 tb(32, 8), tg(32, 32, 3);
    wtrans_kernel<<<tg, tb, 0, stream>>>(Wq, Wk, Wv, Bw);
    gemm_qkv_fused<<<1536, 256, 0, stream>>>(xb, Bw, bq, bk, bv, Qs, Ks, Vh);
    attn_kernel<<<1024, 512, 0, stream>>>(Qs, Ks, Vh, out);
}